// Round 16
// baseline (743.815 us; speedup 1.0000x reference)
//
#include <hip/hip_runtime.h>
#include <cstdint>

typedef __attribute__((ext_vector_type(4))) float f32x4;
typedef __attribute__((ext_vector_type(16))) float f32x16;
typedef __attribute__((ext_vector_type(8))) short bf16x8;
typedef __attribute__((ext_vector_type(4))) short bf16x4;

#define DEV static __device__ __forceinline__

// round-to-nearest-even f32 -> bf16 (bit pattern)
DEV unsigned short f2bf(float f) {
    union { float f; unsigned int u; } v; v.f = f;
    unsigned int u = v.u;
    return (unsigned short)((u + 0x7FFFu + ((u >> 16) & 1u)) >> 16);
}

// async global->LDS 16B per lane; LDS dest = wave-uniform base + lane*16
DEV void async_cp16(const void* g, void* l) {
    __builtin_amdgcn_global_load_lds(
        (const __attribute__((address_space(1))) unsigned int*)g,
        (__attribute__((address_space(3))) unsigned int*)l,
        16, 0, 0);
}

#define BAR __builtin_amdgcn_s_barrier();
#define SCB __builtin_amdgcn_sched_barrier(0);
#define LGKM0 asm volatile("s_waitcnt lgkmcnt(0)");
#define P1 __builtin_amdgcn_s_setprio(1);
#define P0 __builtin_amdgcn_s_setprio(0);
#define VM0 asm volatile("s_waitcnt vmcnt(0)" ::: "memory");
#define VM2 asm volatile("s_waitcnt vmcnt(2)" ::: "memory");

// stage one 128x64 bf16 half-tile (16KB): 512 thr x 2 chunks of 16B.
// linear LDS dest, inverse-swizzled global source. Involution (32-row-aware,
// for 32x32 MFMA frag reads): slot ^= (row&7) ^ ((row>>3)&3).
DEV void stage_half(const unsigned short* __restrict__ g, long kofs,
                    unsigned short* l, int tid, int gpitch) {
#pragma unroll
    for (int i = 0; i < 2; ++i) {
        int c = i * 512 + tid;
        int row = c >> 3;
        int ss = (c & 7) ^ (row & 7) ^ ((row >> 3) & 3);
        async_cp16(g + (long)row * gpitch + kofs + ss * 8,
                   l + (i * 512 + (tid & 448)) * 8);
    }
}

// ---------------------------------------------------------------------------
// 256x256 8-wave GEMM core — R8's proven 8-phase schedule, MFMA shape
// switched to 32x32x16 (half the instructions, same FLOPs, same LDS traffic).
// BK=64, NT K-tiles (even), dbuf'd 128KB LDS.
// LDS bytes: A(buf,h) = buf*32768 + h*16384 ; B(buf,h) = 65536 + same.
// Wave (wr=wv>>2, wcq=wv&3) owns C rows [wr*128,+128) x cols [wcq*64,+64)
// as 4(m) x 2(n) tiles of 32x32; acc[m][n] = f32x16.
// Frags: lane holds A[row=m*32+lw][k: 8 contig at slot q=ks*2+hi5], same map
// for B^T (out-col rows) -> k-pairing correct for any hw k-permutation.
// LDS read swizzle: slot q ^= F, F=(lw&7)^((lw>>3)&3) (m-independent since
// 32-row tiles are 4-aligned in row>>3); 8 lanes/bank-group = b128 minimum.
// Reads are per-lane byte bases oA[ks]/oB[ks] + compile-time immediates.
// Sync/vmcnt ledger byte-identical to R8 (verified passing).
// ---------------------------------------------------------------------------
template <int NT>
DEV void gemm256(const unsigned short* __restrict__ gA,
                 const unsigned short* __restrict__ gB,
                 const int gpitch, unsigned short* lds,
                 f32x16 (&acc)[4][2], const int tid) {
    const int lane = tid & 63;
    const int wv = tid >> 6;
    const int wr = wv >> 2, wcq = wv & 3;
    const int lw = lane & 31, hi5 = lane >> 5;
    const int hb = wcq >> 1;
    const int brq = wcq & 1;
    const int F = (lw & 7) ^ ((lw >> 3) & 3);

    const char* lb = (const char*)lds;
    int oA[4], oB[4];
#pragma unroll
    for (int ks = 0; ks < 4; ++ks) {
        int q = (((ks * 2 + hi5) ^ F) << 4);
        oA[ks] = wr * 16384 + lw * 128 + q;
        oB[ks] = 65536 + hb * 16384 + brq * 8192 + lw * 128 + q;
    }

#define LD8(OFF) (*(const bf16x8*)(lb + (OFF)))
#define RD_AF(MB, CO) _Pragma("unroll") for (int ks = 0; ks < 4; ++ks) {      \
        af[0][ks] = LD8(oA[ks] + (CO) + (MB) * 4096);                         \
        af[1][ks] = LD8(oA[ks] + (CO) + (MB) * 4096 + 4096); }
#define RD_BFA(CO) _Pragma("unroll") for (int ks = 0; ks < 2; ++ks) {         \
        bfA[0][ks] = LD8(oB[ks] + (CO));                                      \
        bfA[1][ks] = LD8(oB[ks] + (CO) + 4096); }
#define RD_BFB(CO) _Pragma("unroll") for (int ks = 0; ks < 2; ++ks) {         \
        bfB[0][ks] = LD8(oB[ks + 2] + (CO));                                  \
        bfB[1][ks] = LD8(oB[ks + 2] + (CO) + 4096); }

    // 8 MFMA: 2 k-steps x 2 m x 2 n; dependent (m,n) pairs 4 apart
#define MM(B_, KB0, MOFF)                                                     \
    _Pragma("unroll") for (int ks = 0; ks < 2; ++ks)                          \
    _Pragma("unroll") for (int m = 0; m < 2; ++m)                             \
    _Pragma("unroll") for (int n = 0; n < 2; ++n)                             \
        acc[(MOFF) + m][n] = __builtin_amdgcn_mfma_f32_32x32x16_bf16(         \
            af[m][(KB0) + ks], B_[n][ks], acc[(MOFF) + m][n], 0, 0, 0);

#define SA0(BUF, K) stage_half(gA, K, lds + ((BUF) * 2 + 0) * 8192, tid, gpitch);
#define SA1(BUF, K) stage_half(gA + (long)128 * gpitch, K, lds + ((BUF) * 2 + 1) * 8192, tid, gpitch);
#define SB0(BUF, K) stage_half(gB, K, lds + 32768 + ((BUF) * 2 + 0) * 8192, tid, gpitch);
#define SB1(BUF, K) stage_half(gB + (long)128 * gpitch, K, lds + 32768 + ((BUF) * 2 + 1) * 8192, tid, gpitch);

    // prologue: K-tile 0 (8 loads) + tile 1's A[h0] (2 loads), wait tile 0
    SA0(0, 0) SA1(0, 0) SB0(0, 0) SB1(0, 0)
    if (NT > 1) {
        SA0(1, 64)
        VM2
    } else {
        VM0
    }
    BAR SCB

    bf16x8 af[2][4], bfA[2][2], bfB[2][2];

    for (int it = 0; it < NT / 2; ++it) {
        const long kO  = (long)(2 * it + 1) * 64;
        const long kE2 = (long)(2 * it + 2) * 64;
        const long kO2 = (long)(2 * it + 3) * 64;
        const bool pf = (it + 1 < NT / 2);

        // ================= tile E (buf0, CO=0) =================
        RD_AF(0, 0) RD_BFA(0)
        SA1(1, kO)
        BAR LGKM0 SCB
        P1 MM(bfA, 0, 0) P0
        BAR
        RD_BFB(0)
        SB0(1, kO)
        BAR LGKM0 SCB
        P1 MM(bfB, 2, 0) P0
        BAR
        RD_AF(2, 0)
        SB1(1, kO)
        BAR LGKM0 SCB
        P1 MM(bfA, 0, 2) P0
        BAR
        if (pf) { SA0(0, kE2) }
        BAR
        P1 MM(bfB, 2, 2) P0
        if (pf) { VM2 } else { VM0 }
        BAR SCB

        // ================= tile O (buf1, CO=32768) =================
        RD_AF(0, 32768) RD_BFA(32768)
        if (pf) { SA1(0, kE2) }
        BAR LGKM0 SCB
        P1 MM(bfA, 0, 0) P0
        BAR
        RD_BFB(32768)
        if (pf) { SB0(0, kE2) }
        BAR LGKM0 SCB
        P1 MM(bfB, 2, 0) P0
        BAR
        RD_AF(2, 32768)
        if (pf) { SB1(0, kE2) }
        BAR LGKM0 SCB
        P1 MM(bfA, 0, 2) P0
        BAR
        if (pf) { SA0(1, kO2) }
        BAR
        P1 MM(bfB, 2, 2) P0
        if (pf) { VM2 }
        BAR SCB
    }
#undef MM
#undef LD8
#undef RD_AF
#undef RD_BFA
#undef RD_BFB
#undef SA0
#undef SA1
#undef SB0
#undef SB1
}

// ---------------------------------------------------------------------------
// Kernel 0: weight prep.
//  w12t[n][k]: n even -> bf16(w0[k]*w1[k][n/2]), n odd -> bf16(w0[k]*w2[k][n/2])
//  w3t[j][n] = bf16(w3[n][j])   (1024 x 512, n contiguous)
// ---------------------------------------------------------------------------
__global__ void prep_w(const float* __restrict__ w0, const float* __restrict__ w1,
                       const float* __restrict__ w2, const float* __restrict__ w3,
                       unsigned short* __restrict__ w12t, unsigned short* __restrict__ w3t) {
    int t = blockIdx.x * 256 + threadIdx.x;
    if (t < 1048576) {
        int n = t >> 10, k = t & 1023;
        const float* src = (n & 1) ? w2 : w1;
        w12t[t] = f2bf(w0[k] * src[k * 512 + (n >> 1)]);
    } else {
        int idx = t - 1048576;
        int j = idx >> 9, n = idx & 511;
        w3t[idx] = f2bf(w3[n * 1024 + j]);
    }
}

// ---------------------------------------------------------------------------
// Kernel 0b: RMSNorm fold. xb[row][k] = bf16(x[row][k] * rsqrt(mean(x^2)))
// ---------------------------------------------------------------------------
__global__ __launch_bounds__(256)
void prep_x(const float* __restrict__ x, unsigned short* __restrict__ xb) {
    const int wv = threadIdx.x >> 6, lane = threadIdx.x & 63;
    const int stride = gridDim.x * 4;
    for (int row = blockIdx.x * 4 + wv; row < 131072; row += stride) {
        const float* xr = x + (long)row * 1024;
        f32x4 v[4];
        float s = 0.f;
#pragma unroll
        for (int c = 0; c < 4; ++c) {
            v[c] = *(const f32x4*)(xr + c * 256 + lane * 4);
            s += v[c].x * v[c].x + v[c].y * v[c].y + v[c].z * v[c].z + v[c].w * v[c].w;
        }
#pragma unroll
        for (int off = 32; off > 0; off >>= 1) s += __shfl_xor(s, off, 64);
        float l = rsqrtf(s * (1.0f / 1024.0f));
        unsigned short* xo = xb + (long)row * 1024;
#pragma unroll
        for (int c = 0; c < 4; ++c) {
            bf16x4 b;
            b.x = (short)f2bf(v[c].x * l);
            b.y = (short)f2bf(v[c].y * l);
            b.z = (short)f2bf(v[c].z * l);
            b.w = (short)f2bf(v[c].w * l);
            *(bf16x4*)(xo + c * 256 + lane * 4) = b;
        }
    }
}

// ---------------------------------------------------------------------------
// Kernel 1: x3 = silu_gate(xb @ w12t^T). 256x256 tile, K=1024 -> 16 K-tiles.
// ---------------------------------------------------------------------------
__global__ __launch_bounds__(512, 2)
void gate_gemm(const unsigned short* __restrict__ xb,
               const unsigned short* __restrict__ w12t,
               unsigned short* __restrict__ x3) {
    __shared__ unsigned short lds[65536];    // 128 KB
    const int tid = threadIdx.x;
    const int lane = tid & 63;
    const int wv = tid >> 6;
    const int wr = wv >> 2, wcq = wv & 3;
    const int lw = lane & 31, hi5 = lane >> 5;

    int bid = blockIdx.x;                    // 2048 blocks
    int wgid = (bid & 7) * 256 + (bid >> 3); // bijective XCD chunks
    const int mt = wgid >> 2, nt = wgid & 3;

    f32x16 acc[4][2];
#pragma unroll
    for (int i = 0; i < 4; ++i)
#pragma unroll
        for (int j = 0; j < 2; ++j)
#pragma unroll
            for (int r = 0; r < 16; ++r) acc[i][j][r] = 0.f;

    gemm256<16>(xb + (long)mt * 256 * 1024, w12t + (long)nt * 256 * 1024,
                1024, lds, acc, tid);

    // ---- epilogue: pair even/odd interleaved cols (gate/up), SiLU, repack --
    // C/D (32x32): col=lane&31, row=(reg&3)+8*(reg>>2)+4*(lane>>5)
    // repack tile [256][136] ushorts (272B pitch)
#pragma unroll
    for (int m = 0; m < 4; ++m)
#pragma unroll
        for (int n = 0; n < 2; ++n)
#pragma unroll
            for (int reg = 0; reg < 16; ++reg) {
                int R = wr * 128 + m * 32 + (reg & 3) + (reg >> 2) * 8 + hi5 * 4;
                float v = acc[m][n][reg];
                float p = __shfl_xor(v, 1, 64);
                float g = (lane & 1) ? p : v;
                float u = (lane & 1) ? v : p;
                float s = (g / (1.0f + __expf(-g))) * u;
                if (!(lane & 1))
                    lds[R * 136 + wcq * 32 + n * 16 + (lw >> 1)] = f2bf(s);
            }
    __syncthreads();
    unsigned short* xg = x3 + (long)(mt * 256) * 512 + nt * 128;
#pragma unroll
    for (int i = 0; i < 8; ++i) {
        int c = i * 512 + tid;               // 4096 chunks of 16B
        int row = c >> 4, ch = c & 15;
        *(bf16x8*)(xg + (long)row * 512 + ch * 8) = *(const bf16x8*)&lds[row * 136 + ch * 8];
    }
}

// ---------------------------------------------------------------------------
// Kernel 2: out = x3 @ w3t (M x 1024 fp32). 256x256 tile, K=512 -> 8 K-tiles.
// ---------------------------------------------------------------------------
__global__ __launch_bounds__(512, 2)
void down_gemm(const unsigned short* __restrict__ x3,
               const unsigned short* __restrict__ w3t,
               float* __restrict__ out) {
    __shared__ unsigned short lds[65536];
    const int tid = threadIdx.x;
    const int lane = tid & 63;
    const int wv = tid >> 6;
    const int wr = wv >> 2, wcq = wv & 3;
    const int lw = lane & 31, hi5 = lane >> 5;

    int bid = blockIdx.x;                    // 2048 blocks
    int wgid = (bid & 7) * 256 + (bid >> 3);
    const int mt = wgid >> 2, nt = wgid & 3;

    f32x16 acc[4][2];
#pragma unroll
    for (int i = 0; i < 4; ++i)
#pragma unroll
        for (int j = 0; j < 2; ++j)
#pragma unroll
            for (int r = 0; r < 16; ++r) acc[i][j][r] = 0.f;

    gemm256<8>(x3 + (long)mt * 256 * 512, w3t + (long)nt * 256 * 512,
               512, lds, acc, tid);

    float* op = out + (long)(mt * 256) * 1024 + nt * 256;
#pragma unroll
    for (int m = 0; m < 4; ++m)
#pragma unroll
        for (int n = 0; n < 2; ++n)
#pragma unroll
            for (int reg = 0; reg < 16; ++reg) {
                int R = wr * 128 + m * 32 + (reg & 3) + (reg >> 2) * 8 + hi5 * 4;
                op[(long)R * 1024 + wcq * 64 + n * 32 + lw] = acc[m][n][reg];
            }
}

// ---------------------------------------------------------------------------
extern "C" void kernel_launch(void* const* d_in, const int* in_sizes, int n_in,
                              void* d_out, int out_size, void* d_ws, size_t ws_size,
                              hipStream_t stream) {
    const float* x  = (const float*)d_in[0];
    const float* w0 = (const float*)d_in[1];
    const float* w1 = (const float*)d_in[2];
    const float* w2 = (const float*)d_in[3];
    const float* w3 = (const float*)d_in[4];
    float* out = (float*)d_out;

    unsigned short* w12t = (unsigned short*)d_ws;           // 2MB
    unsigned short* w3t  = w12t + 1024 * 1024;              // 1MB
    unsigned short* x3   = w3t + 1024 * 512;                // 128MB
    unsigned short* xb   = x3 + (size_t)131072 * 512;       // 256MB

    prep_w<<<dim3(6144), dim3(256), 0, stream>>>(w0, w1, w2, w3, w12t, w3t);
    prep_x<<<dim3(2048), dim3(256), 0, stream>>>(x, xb);
    gate_gemm<<<dim3(2048), dim3(512), 0, stream>>>(xb, w12t, x3);
    down_gemm<<<dim3(2048), dim3(512), 0, stream>>>(x3, w3t, out);
}